// Round 3
// baseline (701.868 us; speedup 1.0000x reference)
//
#include <hip/hip_runtime.h>

#define TSEQ 4096
#define DM 768
#define NHEAD 12
#define HDIM 64
#define SC 0.1803368801111204f  // (1/sqrt(64)) * log2(e)

using f32x4  = __attribute__((ext_vector_type(4))) float;
using bf16x8 = __attribute__((ext_vector_type(8))) short;
using bf16x4 = __attribute__((ext_vector_type(4))) short;

__device__ __forceinline__ short f2bf(float f) {
    union { float f; unsigned u; } x; x.f = f;
    unsigned r = x.u + 0x7FFFu + ((x.u >> 16) & 1u);  // RNE; inputs finite
    return (short)(r >> 16);
}

__device__ __forceinline__ f32x4 mfma16(bf16x8 a, bf16x8 b, f32x4 c) {
    return __builtin_amdgcn_mfma_f32_16x16x32_bf16(a, b, c, 0, 0, 0);
}

// ---------------- GEMM: C = A(4096x768) @ W(768x768)^T + bias ----------------
// Tile 64x64, BK=64, 4 waves; fp32 inputs converted to bf16 during LDS staging.
// EPI 0: bf16 row-major [4096][768]; 1: bf16 transposed [768][4096]; 2: f32 row-major.
template<int EPI>
__global__ __launch_bounds__(256) void gemm_bt(
    const float* __restrict__ A, const float* __restrict__ W,
    const float* __restrict__ bias, void* __restrict__ Cout)
{
    constexpr int K = DM;
    __shared__ __align__(16) short As[64 * 72];
    __shared__ __align__(16) short Bs[64 * 72];
    const int bm = blockIdx.x * 64;
    const int bn = blockIdx.y * 64;
    const int tid = threadIdx.x;
    const int wid = tid >> 6;
    const int lane = tid & 63;
    const int l15 = lane & 15, lq = lane >> 4;

    f32x4 acc[4] = {};

    const int sr = tid >> 3;         // staging row 0..31
    const int sc = (tid & 7) * 8;    // staging col

    for (int k0 = 0; k0 < K; k0 += 64) {
        #pragma unroll
        for (int it = 0; it < 2; ++it) {
            int r = sr + it * 32;
            const float* ga = A + (size_t)(bm + r) * K + k0 + sc;
            f32x4 a0 = *(const f32x4*)ga;
            f32x4 a1 = *(const f32x4*)(ga + 4);
            bf16x8 av;
            #pragma unroll
            for (int j = 0; j < 4; ++j) { av[j] = f2bf(a0[j]); av[4 + j] = f2bf(a1[j]); }
            *(bf16x8*)&As[r * 72 + sc] = av;
            const float* gb = W + (size_t)(bn + r) * K + k0 + sc;
            f32x4 b0 = *(const f32x4*)gb;
            f32x4 b1 = *(const f32x4*)(gb + 4);
            bf16x8 bv;
            #pragma unroll
            for (int j = 0; j < 4; ++j) { bv[j] = f2bf(b0[j]); bv[4 + j] = f2bf(b1[j]); }
            *(bf16x8*)&Bs[r * 72 + sc] = bv;
        }
        __syncthreads();
        #pragma unroll
        for (int ks = 0; ks < 2; ++ks) {
            bf16x8 af = *(bf16x8*)&As[(wid * 16 + l15) * 72 + ks * 32 + lq * 8];
            #pragma unroll
            for (int n = 0; n < 4; ++n) {
                bf16x8 bfv = *(bf16x8*)&Bs[(n * 16 + l15) * 72 + ks * 32 + lq * 8];
                acc[n] = mfma16(af, bfv, acc[n]);
            }
        }
        __syncthreads();
    }

    // C/D layout: col = lane&15 (N), row = (lane>>4)*4 + reg (M)
    const int row0 = bm + wid * 16 + lq * 4;
    #pragma unroll
    for (int n = 0; n < 4; ++n) {
        int col = bn + n * 16 + l15;
        float b = bias[col];
        if (EPI == 1) {
            bf16x4 v;
            #pragma unroll
            for (int r = 0; r < 4; ++r) v[r] = f2bf(acc[n][r] + b);
            *(bf16x4*)((short*)Cout + (size_t)col * TSEQ + row0) = v;
        } else {
            #pragma unroll
            for (int r = 0; r < 4; ++r) {
                float v = acc[n][r] + b;
                if (EPI == 0) ((short*)Cout)[(size_t)(row0 + r) * DM + col] = f2bf(v);
                else          ((float*)Cout)[(size_t)(row0 + r) * DM + col] = v;
            }
        }
    }
}

// ---------------- fused causal attention, barrier-free ----------------
// grid (64 q-tiles heavy-first, 12 heads), 256 threads (4 independent waves,
// 16 q-rows each). Swapped QK^T: s = mfma(K_frag, Q_frag) puts S[q][k] with
// q = lane&15, k 4-consecutive per (n,reg) -> register-direct f32x4 weight
// stores and a 1-scalar row sum. K/V fragments load DIRECTLY from global
// (L2-resident: K+V all heads = 12.6 MB bf16). No __syncthreads anywhere.
__global__ __launch_bounds__(256) void attn_fused(
    const short* __restrict__ Qb, const short* __restrict__ Kb,
    const short* __restrict__ Vt, float* __restrict__ Wout,
    float* __restrict__ AttnO)
{
    const int qt = 63 - blockIdx.x;     // heavy blocks dispatched first
    const int h = blockIdx.y;
    const int q0 = qt * 64;
    const int tid = threadIdx.x, wid = tid >> 6, lane = tid & 63;
    const int l15 = lane & 15, lq = lane >> 4;

    __shared__ __align__(16) short Ps[4][16 * 72];  // per-wave P bounce

    const int nkt = qt + 1;

    // ---- zero strict-upper tail (pure write BW, no sync needed) ----
    {
        float* wbase = Wout + (size_t)h * TSEQ * TSEQ + (size_t)(q0 + wid * 16) * TSEQ;
        f32x4 z = {0.f, 0.f, 0.f, 0.f};
        for (int kt = nkt; kt < 64; ++kt) {
            #pragma unroll
            for (int i = 0; i < 4; ++i) {
                int row = lq + i * 4;
                *(f32x4*)(wbase + (size_t)row * TSEQ + kt * 64 + l15 * 4) = z;
            }
        }
    }

    // Q as MFMA B-operand: row(N)=lane&15 -> q-row, k=(lane>>4)*8
    const short* qp = Qb + (size_t)(q0 + wid * 16 + l15) * DM + h * HDIM + lq * 8;
    bf16x8 qf0 = *(const bf16x8*)qp;
    bf16x8 qf1 = *(const bf16x8*)(qp + 32);

    const short* kbase = Kb + (size_t)h * HDIM;           // + k_row * DM
    const short* vbase = Vt + (size_t)h * HDIM * TSEQ;    // + hd_row * TSEQ
    const int myq = q0 + wid * 16 + l15;                  // this thread's q row

    // ---- phase 1: row sums of exp ----
    f32x4 lacc = {0.f, 0.f, 0.f, 0.f};
    for (int kt = 0; kt < nkt; ++kt) {
        const int k0 = kt * 64;
        f32x4 s[4] = {};
        __builtin_amdgcn_s_setprio(1);
        #pragma unroll
        for (int ks = 0; ks < 2; ++ks) {
            bf16x8 qf = ks ? qf1 : qf0;
            #pragma unroll
            for (int n = 0; n < 4; ++n) {
                bf16x8 kf = *(const bf16x8*)
                    &kbase[(size_t)(k0 + n * 16 + l15) * DM + ks * 32 + lq * 8];
                s[n] = mfma16(kf, qf, s[n]);
            }
        }
        __builtin_amdgcn_s_setprio(0);
        if (kt == qt) {  // diagonal tile: mask k > q
            #pragma unroll
            for (int n = 0; n < 4; ++n) {
                int kb0 = k0 + n * 16 + lq * 4;
                #pragma unroll
                for (int r = 0; r < 4; ++r)
                    lacc[n] += (kb0 + r <= myq) ? exp2f(s[n][r] * SC) : 0.f;
            }
        } else {
            #pragma unroll
            for (int n = 0; n < 4; ++n)
                #pragma unroll
                for (int r = 0; r < 4; ++r)
                    lacc[n] += exp2f(s[n][r] * SC);
        }
    }
    float lsum = (lacc[0] + lacc[1]) + (lacc[2] + lacc[3]);
    lsum += __shfl_xor(lsum, 16);
    lsum += __shfl_xor(lsum, 32);
    const float linv = 1.f / lsum;

    // ---- phase 2: recompute S, register-direct weight stores, P@V ----
    float* wq = Wout + (size_t)h * TSEQ * TSEQ + (size_t)myq * TSEQ;
    f32x4 o[4] = {};
    for (int kt = 0; kt < nkt; ++kt) {
        const int k0 = kt * 64;
        f32x4 s[4] = {};
        __builtin_amdgcn_s_setprio(1);
        #pragma unroll
        for (int ks = 0; ks < 2; ++ks) {
            bf16x8 qf = ks ? qf1 : qf0;
            #pragma unroll
            for (int n = 0; n < 4; ++n) {
                bf16x8 kf = *(const bf16x8*)
                    &kbase[(size_t)(k0 + n * 16 + l15) * DM + ks * 32 + lq * 8];
                s[n] = mfma16(kf, qf, s[n]);
            }
        }
        __builtin_amdgcn_s_setprio(0);
        const bool diag = (kt == qt);
        #pragma unroll
        for (int n = 0; n < 4; ++n) {
            const int kb0 = k0 + n * 16 + lq * 4;
            f32x4 p;
            #pragma unroll
            for (int r = 0; r < 4; ++r) {
                float e = exp2f(s[n][r] * SC) * linv;
                p[r] = (diag && (kb0 + r > myq)) ? 0.f : e;
            }
            *(f32x4*)(wq + kb0) = p;  // 4 consecutive k, exact fp32
            bf16x4 pb;
            #pragma unroll
            for (int r = 0; r < 4; ++r) pb[r] = f2bf(p[r]);
            *(bf16x4*)&Ps[wid][l15 * 72 + n * 16 + lq * 4] = pb;
        }
        // P @ V: A-frag rows=q from Ps, B-frag = V^T fragment direct from global
        __builtin_amdgcn_s_setprio(1);
        #pragma unroll
        for (int ks = 0; ks < 2; ++ks) {
            bf16x8 pf = *(bf16x8*)&Ps[wid][l15 * 72 + ks * 32 + lq * 8];
            #pragma unroll
            for (int n = 0; n < 4; ++n) {
                bf16x8 vf = *(const bf16x8*)
                    &vbase[(size_t)(n * 16 + l15) * TSEQ + k0 + ks * 32 + lq * 8];
                o[n] = mfma16(pf, vf, o[n]);
            }
        }
        __builtin_amdgcn_s_setprio(0);
    }

    // ---- epilogue: attention output (row = lq*4+r, col = n*16+l15) ----
    #pragma unroll
    for (int n = 0; n < 4; ++n) {
        int col = h * HDIM + n * 16 + l15;
        #pragma unroll
        for (int r = 0; r < 4; ++r) {
            int row = q0 + wid * 16 + lq * 4 + r;
            AttnO[(size_t)row * DM + col] = o[n][r];
        }
    }
}

extern "C" void kernel_launch(void* const* d_in, const int* in_sizes, int n_in,
                              void* d_out, int out_size, void* d_ws, size_t ws_size,
                              hipStream_t stream)
{
    const float* q_in = (const float*)d_in[0];
    const float* k_in = (const float*)d_in[1];
    const float* v_in = (const float*)d_in[2];
    // d_in[3] = causal mask (triu, k=1) — structure known, not read
    const float* Wq_w = (const float*)d_in[4];
    const float* Wq_b = (const float*)d_in[5];
    const float* Wk_w = (const float*)d_in[6];
    const float* Wk_b = (const float*)d_in[7];
    const float* Wv_w = (const float*)d_in[8];
    const float* Wv_b = (const float*)d_in[9];
    const float* W0_w = (const float*)d_in[10];
    const float* W0_b = (const float*)d_in[11];

    float* out  = (float*)d_out;                       // [4096][768] fp32
    float* wout = out + (size_t)TSEQ * DM;             // [12][4096][4096] fp32

    short* Qb = (short*)d_ws;                          // [4096][768] bf16
    short* Kb = Qb + (size_t)TSEQ * DM;                // [4096][768] bf16
    short* Vt = Kb + (size_t)TSEQ * DM;                // [768][4096] bf16 (V^T)
    float* AttnO = (float*)(Vt + (size_t)TSEQ * DM);   // [4096][768] fp32

    dim3 gg(TSEQ / 64, DM / 64);
    gemm_bt<0><<<gg, 256, 0, stream>>>(q_in, Wq_w, Wq_b, Qb);
    gemm_bt<0><<<gg, 256, 0, stream>>>(k_in, Wk_w, Wk_b, Kb);
    gemm_bt<1><<<gg, 256, 0, stream>>>(v_in, Wv_w, Wv_b, Vt);
    attn_fused<<<dim3(64, NHEAD), 256, 0, stream>>>(Qb, Kb, Vt, wout, AttnO);
    gemm_bt<2><<<gg, 256, 0, stream>>>(AttnO, W0_w, W0_b, out);
}

// Round 4
// 370.314 us; speedup vs baseline: 1.8953x; 1.8953x over previous
//
#include <hip/hip_runtime.h>

#define TSEQ 4096
#define DM 768
#define NHEAD 12
#define HDIM 64
#define SC 0.1803368801111204f  // (1/sqrt(64)) * log2(e)

using f32x4  = __attribute__((ext_vector_type(4))) float;
using bf16x8 = __attribute__((ext_vector_type(8))) short;
using bf16x4 = __attribute__((ext_vector_type(4))) short;

__device__ __forceinline__ short f2bf(float f) {
    union { float f; unsigned u; } x; x.f = f;
    unsigned r = x.u + 0x7FFFu + ((x.u >> 16) & 1u);  // RNE; inputs finite
    return (short)(r >> 16);
}

__device__ __forceinline__ f32x4 mfma16(bf16x8 a, bf16x8 b, f32x4 c) {
    return __builtin_amdgcn_mfma_f32_16x16x32_bf16(a, b, c, 0, 0, 0);
}

// ---------------- fused QKV projection GEMMs (one dispatch, grid.z=3) --------
// C = A(4096x768) @ W(768x768)^T + bias. Tile 64x64, BK=64, 4 waves.
// z=0: Q -> bf16 row-major; z=1: K -> bf16 row-major; z=2: V -> bf16 transposed.
__global__ __launch_bounds__(256) void gemm_qkv(
    const float* __restrict__ q_in, const float* __restrict__ k_in,
    const float* __restrict__ v_in,
    const float* __restrict__ Wq_w, const float* __restrict__ Wq_b,
    const float* __restrict__ Wk_w, const float* __restrict__ Wk_b,
    const float* __restrict__ Wv_w, const float* __restrict__ Wv_b,
    short* __restrict__ Qb, short* __restrict__ Kb, short* __restrict__ Vt)
{
    constexpr int K = DM;
    __shared__ __align__(16) short As[64 * 72];
    __shared__ __align__(16) short Bs[64 * 72];
    const int z = blockIdx.z;
    const float* A    = (z == 0) ? q_in : (z == 1) ? k_in : v_in;
    const float* W    = (z == 0) ? Wq_w : (z == 1) ? Wk_w : Wv_w;
    const float* bias = (z == 0) ? Wq_b : (z == 1) ? Wk_b : Wv_b;

    const int bm = blockIdx.x * 64;
    const int bn = blockIdx.y * 64;
    const int tid = threadIdx.x;
    const int wid = tid >> 6;
    const int lane = tid & 63;
    const int l15 = lane & 15, lq = lane >> 4;

    f32x4 acc[4] = {};
    const int sr = tid >> 3;
    const int sc = (tid & 7) * 8;

    for (int k0 = 0; k0 < K; k0 += 64) {
        #pragma unroll
        for (int it = 0; it < 2; ++it) {
            int r = sr + it * 32;
            const float* ga = A + (size_t)(bm + r) * K + k0 + sc;
            f32x4 a0 = *(const f32x4*)ga;
            f32x4 a1 = *(const f32x4*)(ga + 4);
            bf16x8 av;
            #pragma unroll
            for (int j = 0; j < 4; ++j) { av[j] = f2bf(a0[j]); av[4 + j] = f2bf(a1[j]); }
            *(bf16x8*)&As[r * 72 + sc] = av;
            const float* gb = W + (size_t)(bn + r) * K + k0 + sc;
            f32x4 b0 = *(const f32x4*)gb;
            f32x4 b1 = *(const f32x4*)(gb + 4);
            bf16x8 bv;
            #pragma unroll
            for (int j = 0; j < 4; ++j) { bv[j] = f2bf(b0[j]); bv[4 + j] = f2bf(b1[j]); }
            *(bf16x8*)&Bs[r * 72 + sc] = bv;
        }
        __syncthreads();
        __builtin_amdgcn_s_setprio(1);
        #pragma unroll
        for (int ks = 0; ks < 2; ++ks) {
            bf16x8 af = *(bf16x8*)&As[(wid * 16 + l15) * 72 + ks * 32 + lq * 8];
            #pragma unroll
            for (int n = 0; n < 4; ++n) {
                bf16x8 bfv = *(bf16x8*)&Bs[(n * 16 + l15) * 72 + ks * 32 + lq * 8];
                acc[n] = mfma16(af, bfv, acc[n]);
            }
        }
        __builtin_amdgcn_s_setprio(0);
        __syncthreads();
    }

    const int row0 = bm + wid * 16 + lq * 4;
    #pragma unroll
    for (int n = 0; n < 4; ++n) {
        int col = bn + n * 16 + l15;
        float b = bias[col];
        if (z == 2) {  // V transposed [768][4096]
            bf16x4 v;
            #pragma unroll
            for (int r = 0; r < 4; ++r) v[r] = f2bf(acc[n][r] + b);
            *(bf16x4*)(Vt + (size_t)col * TSEQ + row0) = v;
        } else {
            short* dst = (z == 0) ? Qb : Kb;
            #pragma unroll
            for (int r = 0; r < 4; ++r)
                dst[(size_t)(row0 + r) * DM + col] = f2bf(acc[n][r] + b);
        }
    }
}

// ---------------- output GEMM: out = AttnO(4096x768) @ W0^T + b0 (fp32) ------
__global__ __launch_bounds__(256) void gemm_out(
    const float* __restrict__ A, const float* __restrict__ W,
    const float* __restrict__ bias, float* __restrict__ Cout)
{
    constexpr int K = DM;
    __shared__ __align__(16) short As[64 * 72];
    __shared__ __align__(16) short Bs[64 * 72];
    const int bm = blockIdx.x * 64;
    const int bn = blockIdx.y * 64;
    const int tid = threadIdx.x;
    const int wid = tid >> 6;
    const int lane = tid & 63;
    const int l15 = lane & 15, lq = lane >> 4;

    f32x4 acc[4] = {};
    const int sr = tid >> 3;
    const int sc = (tid & 7) * 8;

    for (int k0 = 0; k0 < K; k0 += 64) {
        #pragma unroll
        for (int it = 0; it < 2; ++it) {
            int r = sr + it * 32;
            const float* ga = A + (size_t)(bm + r) * K + k0 + sc;
            f32x4 a0 = *(const f32x4*)ga;
            f32x4 a1 = *(const f32x4*)(ga + 4);
            bf16x8 av;
            #pragma unroll
            for (int j = 0; j < 4; ++j) { av[j] = f2bf(a0[j]); av[4 + j] = f2bf(a1[j]); }
            *(bf16x8*)&As[r * 72 + sc] = av;
            const float* gb = W + (size_t)(bn + r) * K + k0 + sc;
            f32x4 b0 = *(const f32x4*)gb;
            f32x4 b1 = *(const f32x4*)(gb + 4);
            bf16x8 bv;
            #pragma unroll
            for (int j = 0; j < 4; ++j) { bv[j] = f2bf(b0[j]); bv[4 + j] = f2bf(b1[j]); }
            *(bf16x8*)&Bs[r * 72 + sc] = bv;
        }
        __syncthreads();
        __builtin_amdgcn_s_setprio(1);
        #pragma unroll
        for (int ks = 0; ks < 2; ++ks) {
            bf16x8 af = *(bf16x8*)&As[(wid * 16 + l15) * 72 + ks * 32 + lq * 8];
            #pragma unroll
            for (int n = 0; n < 4; ++n) {
                bf16x8 bfv = *(bf16x8*)&Bs[(n * 16 + l15) * 72 + ks * 32 + lq * 8];
                acc[n] = mfma16(af, bfv, acc[n]);
            }
        }
        __builtin_amdgcn_s_setprio(0);
        __syncthreads();
    }

    const int row0 = bm + wid * 16 + lq * 4;
    #pragma unroll
    for (int n = 0; n < 4; ++n) {
        int col = bn + n * 16 + l15;
        float b = bias[col];
        #pragma unroll
        for (int r = 0; r < 4; ++r)
            Cout[(size_t)(row0 + r) * DM + col] = acc[n][r] + b;
    }
}

// ---------------- fused causal attention ----------------
// grid (64 q-tiles heavy-first, 12 heads), 256 threads (4 waves, 16 q-rows).
// Swapped QK^T (mfma(K,Q)): thread owns q-row = lane&15, k = n*16+lq*4+r.
// Phase 1: exp row-sums, K staged in 128-row LDS chunks (2 tiles/barrier).
// Phase 2: recompute S, register-direct f32x4 weight stores, P@V with K,V
// staged double-buffered in LDS. Upper-triangle zero fill fused.
__global__ __launch_bounds__(256) void attn_fused(
    const short* __restrict__ Qb, const short* __restrict__ Kb,
    const short* __restrict__ Vt, float* __restrict__ Wout,
    float* __restrict__ AttnO)
{
    const int qt = 63 - blockIdx.x;     // heavy blocks first
    const int h = blockIdx.y;
    const int q0 = qt * 64;
    const int tid = threadIdx.x, wid = tid >> 6, lane = tid & 63;
    const int l15 = lane & 15, lq = lane >> 4;

    // one pool, aliased: phase1 K-chunks [2][128*72]=36864B;
    // phase2 Ks[2][64*72]+Vs[2][64*72]+Ps[4][16*72]=46080B
    __shared__ __align__(16) short lds[23040];

    const int nkt = qt + 1;

    // ---- zero strict-upper tail ----
    {
        float* wbase = Wout + (size_t)h * TSEQ * TSEQ + (size_t)(q0 + wid * 16) * TSEQ;
        f32x4 z = {0.f, 0.f, 0.f, 0.f};
        for (int kt = nkt; kt < 64; ++kt) {
            #pragma unroll
            for (int i = 0; i < 4; ++i)
                *(f32x4*)(wbase + (size_t)(lq + i * 4) * TSEQ + kt * 64 + l15 * 4) = z;
        }
    }

    // Q as MFMA B-operand: q-row = lane&15, k = (lane>>4)*8
    const short* qp = Qb + (size_t)(q0 + wid * 16 + l15) * DM + h * HDIM + lq * 8;
    bf16x8 qf0 = *(const bf16x8*)qp;
    bf16x8 qf1 = *(const bf16x8*)(qp + 32);

    const short* kbase = Kb + (size_t)h * HDIM;        // + k_row * DM
    const short* vbase = Vt + (size_t)h * HDIM * TSEQ; // + hd_row * TSEQ
    const int myq = q0 + wid * 16 + l15;

    const int srow = tid >> 3;          // 0..31
    const int scol = (tid & 7) * 8;     // 0..56

    // ---- phase 1: row sums of exp; K staged in 128-row chunks ----
    const int nch = (nkt + 1) >> 1;
    auto stageKbig = [&](int c, int b) {
        const int base_k = c * 128;
        const int iters = (nkt * 64 - base_k) >= 128 ? 4 : 2;
        short* dst = lds + b * (128 * 72);
        for (int it = 0; it < iters; ++it) {
            int r = srow + it * 32;
            *(bf16x8*)&dst[r * 72 + scol] =
                *(const bf16x8*)&kbase[(size_t)(base_k + r) * DM + scol];
        }
    };

    f32x4 lacc = {0.f, 0.f, 0.f, 0.f};
    stageKbig(0, 0);
    __syncthreads();
    for (int c = 0; c < nch; ++c) {
        const int b = c & 1;
        if (c + 1 < nch) stageKbig(c + 1, b ^ 1);
        const short* kb = lds + b * (128 * 72);
        #pragma unroll
        for (int t = 0; t < 2; ++t) {
            const int kt = c * 2 + t;
            if (kt >= nkt) break;
            f32x4 s[4] = {};
            __builtin_amdgcn_s_setprio(1);
            #pragma unroll
            for (int ks = 0; ks < 2; ++ks) {
                bf16x8 qf = ks ? qf1 : qf0;
                #pragma unroll
                for (int n = 0; n < 4; ++n) {
                    bf16x8 kf = *(const bf16x8*)
                        &kb[(t * 64 + n * 16 + l15) * 72 + ks * 32 + lq * 8];
                    s[n] = mfma16(kf, qf, s[n]);
                }
            }
            __builtin_amdgcn_s_setprio(0);
            if (kt == qt) {  // diagonal: mask k > q
                #pragma unroll
                for (int n = 0; n < 4; ++n) {
                    int kb0 = kt * 64 + n * 16 + lq * 4;
                    #pragma unroll
                    for (int r = 0; r < 4; ++r)
                        lacc[n] += (kb0 + r <= myq) ? exp2f(s[n][r] * SC) : 0.f;
                }
            } else {
                #pragma unroll
                for (int n = 0; n < 4; ++n)
                    #pragma unroll
                    for (int r = 0; r < 4; ++r)
                        lacc[n] += exp2f(s[n][r] * SC);
            }
        }
        __syncthreads();
    }
    float lsum = (lacc[0] + lacc[1]) + (lacc[2] + lacc[3]);
    lsum += __shfl_xor(lsum, 16);
    lsum += __shfl_xor(lsum, 32);
    const float linv = 1.f / lsum;

    // ---- phase 2: recompute S, weight stores, P@V ----
    short* Ks2 = lds;                       // [2][64*72]
    short* Vs2 = lds + 2 * 64 * 72;         // [2][64*72]
    short* Psw = lds + 4 * 64 * 72 + wid * (16 * 72);

    auto stageK2 = [&](int kt, int b) {
        short* dst = Ks2 + b * (64 * 72);
        #pragma unroll
        for (int it = 0; it < 2; ++it) {
            int r = srow + it * 32;
            *(bf16x8*)&dst[r * 72 + scol] =
                *(const bf16x8*)&kbase[(size_t)(kt * 64 + r) * DM + scol];
        }
    };
    auto stageV2 = [&](int kt, int b) {
        short* dst = Vs2 + b * (64 * 72);
        #pragma unroll
        for (int it = 0; it < 2; ++it) {
            int r = srow + it * 32;
            *(bf16x8*)&dst[r * 72 + scol] =
                *(const bf16x8*)&vbase[(size_t)r * TSEQ + kt * 64 + scol];
        }
    };

    float* wq = Wout + (size_t)h * TSEQ * TSEQ + (size_t)myq * TSEQ;
    f32x4 o[4] = {};
    stageK2(0, 0);
    stageV2(0, 0);
    __syncthreads();
    for (int kt = 0; kt < nkt; ++kt) {
        const int b = kt & 1;
        if (kt + 1 < nkt) { stageK2(kt + 1, b ^ 1); stageV2(kt + 1, b ^ 1); }
        f32x4 s[4] = {};
        __builtin_amdgcn_s_setprio(1);
        #pragma unroll
        for (int ks = 0; ks < 2; ++ks) {
            bf16x8 qf = ks ? qf1 : qf0;
            #pragma unroll
            for (int n = 0; n < 4; ++n) {
                bf16x8 kf = *(const bf16x8*)
                    &Ks2[b * (64 * 72) + (n * 16 + l15) * 72 + ks * 32 + lq * 8];
                s[n] = mfma16(kf, qf, s[n]);
            }
        }
        __builtin_amdgcn_s_setprio(0);
        const bool diag = (kt == qt);
        #pragma unroll
        for (int n = 0; n < 4; ++n) {
            const int kb0 = kt * 64 + n * 16 + lq * 4;
            f32x4 p;
            #pragma unroll
            for (int r = 0; r < 4; ++r) {
                float e = exp2f(s[n][r] * SC) * linv;
                p[r] = (diag && (kb0 + r > myq)) ? 0.f : e;
            }
            *(f32x4*)(wq + kb0) = p;  // exact fp32 weights, 64B sectors
            bf16x4 pb;
            #pragma unroll
            for (int r = 0; r < 4; ++r) pb[r] = f2bf(p[r]);
            *(bf16x4*)&Psw[l15 * 72 + n * 16 + lq * 4] = pb;
        }
        // P @ V: A-frag = P (q rows) from per-wave Ps, B-frag = V^T from LDS
        __builtin_amdgcn_s_setprio(1);
        #pragma unroll
        for (int ks = 0; ks < 2; ++ks) {
            bf16x8 pf = *(bf16x8*)&Psw[l15 * 72 + ks * 32 + lq * 8];
            #pragma unroll
            for (int n = 0; n < 4; ++n) {
                bf16x8 vf = *(const bf16x8*)
                    &Vs2[b * (64 * 72) + (n * 16 + l15) * 72 + ks * 32 + lq * 8];
                o[n] = mfma16(pf, vf, o[n]);
            }
        }
        __builtin_amdgcn_s_setprio(0);
        __syncthreads();
    }

    // ---- epilogue: O (row = q0+wid*16+lq*4+r, col = h*64+n*16+l15) ----
    #pragma unroll
    for (int n = 0; n < 4; ++n) {
        int col = h * HDIM + n * 16 + l15;
        #pragma unroll
        for (int r = 0; r < 4; ++r) {
            int row = q0 + wid * 16 + lq * 4 + r;
            AttnO[(size_t)row * DM + col] = o[n][r];
        }
    }
}

extern "C" void kernel_launch(void* const* d_in, const int* in_sizes, int n_in,
                              void* d_out, int out_size, void* d_ws, size_t ws_size,
                              hipStream_t stream)
{
    const float* q_in = (const float*)d_in[0];
    const float* k_in = (const float*)d_in[1];
    const float* v_in = (const float*)d_in[2];
    // d_in[3] = causal mask (triu, k=1) — structure known, not read
    const float* Wq_w = (const float*)d_in[4];
    const float* Wq_b = (const float*)d_in[5];
    const float* Wk_w = (const float*)d_in[6];
    const float* Wk_b = (const float*)d_in[7];
    const float* Wv_w = (const float*)d_in[8];
    const float* Wv_b = (const float*)d_in[9];
    const float* W0_w = (const float*)d_in[10];
    const float* W0_b = (const float*)d_in[11];

    float* out  = (float*)d_out;                       // [4096][768] fp32
    float* wout = out + (size_t)TSEQ * DM;             // [12][4096][4096] fp32

    short* Qb = (short*)d_ws;                          // [4096][768] bf16
    short* Kb = Qb + (size_t)TSEQ * DM;                // [4096][768] bf16
    short* Vt = Kb + (size_t)TSEQ * DM;                // [768][4096] bf16 (V^T)
    float* AttnO = (float*)(Vt + (size_t)TSEQ * DM);   // [4096][768] fp32

    gemm_qkv<<<dim3(TSEQ / 64, DM / 64, 3), 256, 0, stream>>>(
        q_in, k_in, v_in, Wq_w, Wq_b, Wk_w, Wk_b, Wv_w, Wv_b, Qb, Kb, Vt);
    attn_fused<<<dim3(64, NHEAD), 256, 0, stream>>>(Qb, Kb, Vt, wout, AttnO);
    gemm_out<<<dim3(TSEQ / 64, DM / 64), 256, 0, stream>>>(AttnO, W0_w, W0_b, out);
}

// Round 5
// 342.699 us; speedup vs baseline: 2.0481x; 1.0806x over previous
//
#include <hip/hip_runtime.h>

#define TSEQ 4096
#define DM 768
#define NHEAD 12
#define HDIM 64
#define SC 0.1803368801111204f  // (1/sqrt(64)) * log2(e)

using f32x4  = __attribute__((ext_vector_type(4))) float;
using bf16x8 = __attribute__((ext_vector_type(8))) short;
using bf16x4 = __attribute__((ext_vector_type(4))) short;

// Barrier that waits only LDS ops — global stores stay in flight (no vmcnt(0)
// drain; the T4 "never vmcnt(0) in the main loop" rule).
#define LGKM_BARRIER() asm volatile("s_waitcnt lgkmcnt(0)\n\ts_barrier" ::: "memory")

__device__ __forceinline__ short f2bf(float f) {
    union { float f; unsigned u; } x; x.f = f;
    unsigned r = x.u + 0x7FFFu + ((x.u >> 16) & 1u);  // RNE; inputs finite
    return (short)(r >> 16);
}

__device__ __forceinline__ f32x4 mfma16(bf16x8 a, bf16x8 b, f32x4 c) {
    return __builtin_amdgcn_mfma_f32_16x16x32_bf16(a, b, c, 0, 0, 0);
}

// ---------------- fused QKV projection GEMMs (one dispatch, grid.z=3) --------
// C = A(4096x768) @ W(768x768)^T + bias. Tile 64x64, BK=64, 4 waves.
// z=0: Q -> bf16 row-major; z=1: K -> bf16 row-major; z=2: V -> bf16 transposed.
__global__ __launch_bounds__(256) void gemm_qkv(
    const float* __restrict__ q_in, const float* __restrict__ k_in,
    const float* __restrict__ v_in,
    const float* __restrict__ Wq_w, const float* __restrict__ Wq_b,
    const float* __restrict__ Wk_w, const float* __restrict__ Wk_b,
    const float* __restrict__ Wv_w, const float* __restrict__ Wv_b,
    short* __restrict__ Qb, short* __restrict__ Kb, short* __restrict__ Vt)
{
    constexpr int K = DM;
    __shared__ __align__(16) short As[64 * 72];
    __shared__ __align__(16) short Bs[64 * 72];
    const int z = blockIdx.z;
    const float* A    = (z == 0) ? q_in : (z == 1) ? k_in : v_in;
    const float* W    = (z == 0) ? Wq_w : (z == 1) ? Wk_w : Wv_w;
    const float* bias = (z == 0) ? Wq_b : (z == 1) ? Wk_b : Wv_b;

    const int bm = blockIdx.x * 64;
    const int bn = blockIdx.y * 64;
    const int tid = threadIdx.x;
    const int wid = tid >> 6;
    const int lane = tid & 63;
    const int l15 = lane & 15, lq = lane >> 4;

    f32x4 acc[4] = {};
    const int sr = tid >> 3;
    const int sc = (tid & 7) * 8;

    for (int k0 = 0; k0 < K; k0 += 64) {
        #pragma unroll
        for (int it = 0; it < 2; ++it) {
            int r = sr + it * 32;
            const float* ga = A + (size_t)(bm + r) * K + k0 + sc;
            f32x4 a0 = *(const f32x4*)ga;
            f32x4 a1 = *(const f32x4*)(ga + 4);
            bf16x8 av;
            #pragma unroll
            for (int j = 0; j < 4; ++j) { av[j] = f2bf(a0[j]); av[4 + j] = f2bf(a1[j]); }
            *(bf16x8*)&As[r * 72 + sc] = av;
            const float* gb = W + (size_t)(bn + r) * K + k0 + sc;
            f32x4 b0 = *(const f32x4*)gb;
            f32x4 b1 = *(const f32x4*)(gb + 4);
            bf16x8 bv;
            #pragma unroll
            for (int j = 0; j < 4; ++j) { bv[j] = f2bf(b0[j]); bv[4 + j] = f2bf(b1[j]); }
            *(bf16x8*)&Bs[r * 72 + sc] = bv;
        }
        LGKM_BARRIER();
        __builtin_amdgcn_s_setprio(1);
        #pragma unroll
        for (int ks = 0; ks < 2; ++ks) {
            bf16x8 af = *(bf16x8*)&As[(wid * 16 + l15) * 72 + ks * 32 + lq * 8];
            #pragma unroll
            for (int n = 0; n < 4; ++n) {
                bf16x8 bfv = *(bf16x8*)&Bs[(n * 16 + l15) * 72 + ks * 32 + lq * 8];
                acc[n] = mfma16(af, bfv, acc[n]);
            }
        }
        __builtin_amdgcn_s_setprio(0);
        LGKM_BARRIER();
    }

    const int row0 = bm + wid * 16 + lq * 4;
    #pragma unroll
    for (int n = 0; n < 4; ++n) {
        int col = bn + n * 16 + l15;
        float b = bias[col];
        if (z == 2) {  // V transposed [768][4096]
            bf16x4 v;
            #pragma unroll
            for (int r = 0; r < 4; ++r) v[r] = f2bf(acc[n][r] + b);
            *(bf16x4*)(Vt + (size_t)col * TSEQ + row0) = v;
        } else {
            short* dst = (z == 0) ? Qb : Kb;
            #pragma unroll
            for (int r = 0; r < 4; ++r)
                dst[(size_t)(row0 + r) * DM + col] = f2bf(acc[n][r] + b);
        }
    }
}

// ---------------- output GEMM: out = AttnO(4096x768) @ W0^T + b0 (fp32) ------
__global__ __launch_bounds__(256) void gemm_out(
    const float* __restrict__ A, const float* __restrict__ W,
    const float* __restrict__ bias, float* __restrict__ Cout)
{
    constexpr int K = DM;
    __shared__ __align__(16) short As[64 * 72];
    __shared__ __align__(16) short Bs[64 * 72];
    const int bm = blockIdx.x * 64;
    const int bn = blockIdx.y * 64;
    const int tid = threadIdx.x;
    const int wid = tid >> 6;
    const int lane = tid & 63;
    const int l15 = lane & 15, lq = lane >> 4;

    f32x4 acc[4] = {};
    const int sr = tid >> 3;
    const int sc = (tid & 7) * 8;

    for (int k0 = 0; k0 < K; k0 += 64) {
        #pragma unroll
        for (int it = 0; it < 2; ++it) {
            int r = sr + it * 32;
            const float* ga = A + (size_t)(bm + r) * K + k0 + sc;
            f32x4 a0 = *(const f32x4*)ga;
            f32x4 a1 = *(const f32x4*)(ga + 4);
            bf16x8 av;
            #pragma unroll
            for (int j = 0; j < 4; ++j) { av[j] = f2bf(a0[j]); av[4 + j] = f2bf(a1[j]); }
            *(bf16x8*)&As[r * 72 + sc] = av;
            const float* gb = W + (size_t)(bn + r) * K + k0 + sc;
            f32x4 b0 = *(const f32x4*)gb;
            f32x4 b1 = *(const f32x4*)(gb + 4);
            bf16x8 bv;
            #pragma unroll
            for (int j = 0; j < 4; ++j) { bv[j] = f2bf(b0[j]); bv[4 + j] = f2bf(b1[j]); }
            *(bf16x8*)&Bs[r * 72 + sc] = bv;
        }
        LGKM_BARRIER();
        __builtin_amdgcn_s_setprio(1);
        #pragma unroll
        for (int ks = 0; ks < 2; ++ks) {
            bf16x8 af = *(bf16x8*)&As[(wid * 16 + l15) * 72 + ks * 32 + lq * 8];
            #pragma unroll
            for (int n = 0; n < 4; ++n) {
                bf16x8 bfv = *(bf16x8*)&Bs[(n * 16 + l15) * 72 + ks * 32 + lq * 8];
                acc[n] = mfma16(af, bfv, acc[n]);
            }
        }
        __builtin_amdgcn_s_setprio(0);
        LGKM_BARRIER();
    }

    const int row0 = bm + wid * 16 + lq * 4;
    #pragma unroll
    for (int n = 0; n < 4; ++n) {
        int col = bn + n * 16 + l15;
        float b = bias[col];
        #pragma unroll
        for (int r = 0; r < 4; ++r)
            Cout[(size_t)(row0 + r) * DM + col] = acc[n][r] + b;
    }
}

// ---------------- fused causal attention ----------------
// grid (64 q-tiles heavy-first, 12 heads), 256 threads (4 waves, 16 q-rows).
// Swapped QK^T (mfma(K,Q)): thread owns q-row = lane&15, k = n*16+lq*4+r.
// Phase 1: exp row-sums, K staged in 128-row LDS chunks.
// Phase 2: recompute S, NT register-direct f32x4 weight stores, P@V with K,V
// reg-staged (async split) into double-buffered LDS. lgkm-only barriers
// throughout -> weight stores drain in the background.
__global__ __launch_bounds__(256) void attn_fused(
    const short* __restrict__ Qb, const short* __restrict__ Kb,
    const short* __restrict__ Vt, float* __restrict__ Wout,
    float* __restrict__ AttnO)
{
    const int qt = 63 - blockIdx.x;     // heavy blocks first
    const int h = blockIdx.y;
    const int q0 = qt * 64;
    const int tid = threadIdx.x, wid = tid >> 6, lane = tid & 63;
    const int l15 = lane & 15, lq = lane >> 4;

    // one pool, aliased: phase1 K-chunks [2][128*72]=36864B;
    // phase2 Ks[2][64*72]+Vs[2][64*72]+Ps[4][16*72]=46080B
    __shared__ __align__(16) short lds[23040];

    const int nkt = qt + 1;

    // ---- zero strict-upper tail (NT stores, fire-and-forget) ----
    {
        float* wbase = Wout + (size_t)h * TSEQ * TSEQ + (size_t)(q0 + wid * 16) * TSEQ;
        f32x4 z = {0.f, 0.f, 0.f, 0.f};
        for (int kt = nkt; kt < 64; ++kt) {
            #pragma unroll
            for (int i = 0; i < 4; ++i)
                __builtin_nontemporal_store(
                    z, (f32x4*)(wbase + (size_t)(lq + i * 4) * TSEQ + kt * 64 + l15 * 4));
        }
    }

    // Q as MFMA B-operand: q-row = lane&15, k = (lane>>4)*8
    const short* qp = Qb + (size_t)(q0 + wid * 16 + l15) * DM + h * HDIM + lq * 8;
    bf16x8 qf0 = *(const bf16x8*)qp;
    bf16x8 qf1 = *(const bf16x8*)(qp + 32);

    const short* kbase = Kb + (size_t)h * HDIM;        // + k_row * DM
    const short* vbase = Vt + (size_t)h * HDIM * TSEQ; // + hd_row * TSEQ
    const int myq = q0 + wid * 16 + l15;

    const int srow = tid >> 3;          // 0..31
    const int scol = (tid & 7) * 8;     // 0..56

    // ---- phase 1: row sums of exp; K staged in 128-row chunks ----
    const int nch = (nkt + 1) >> 1;
    auto stageKbig = [&](int c, int b) {
        const int base_k = c * 128;
        const int iters = (nkt * 64 - base_k) >= 128 ? 4 : 2;
        short* dst = lds + b * (128 * 72);
        for (int it = 0; it < iters; ++it) {
            int r = srow + it * 32;
            *(bf16x8*)&dst[r * 72 + scol] =
                *(const bf16x8*)&kbase[(size_t)(base_k + r) * DM + scol];
        }
    };

    f32x4 lacc = {0.f, 0.f, 0.f, 0.f};
    stageKbig(0, 0);
    LGKM_BARRIER();
    for (int c = 0; c < nch; ++c) {
        const int b = c & 1;
        if (c + 1 < nch) stageKbig(c + 1, b ^ 1);
        const short* kb = lds + b * (128 * 72);
        #pragma unroll
        for (int t = 0; t < 2; ++t) {
            const int kt = c * 2 + t;
            if (kt >= nkt) break;
            f32x4 s[4] = {};
            __builtin_amdgcn_s_setprio(1);
            #pragma unroll
            for (int ks = 0; ks < 2; ++ks) {
                bf16x8 qf = ks ? qf1 : qf0;
                #pragma unroll
                for (int n = 0; n < 4; ++n) {
                    bf16x8 kf = *(const bf16x8*)
                        &kb[(t * 64 + n * 16 + l15) * 72 + ks * 32 + lq * 8];
                    s[n] = mfma16(kf, qf, s[n]);
                }
            }
            __builtin_amdgcn_s_setprio(0);
            if (kt == qt) {  // diagonal: mask k > q
                #pragma unroll
                for (int n = 0; n < 4; ++n) {
                    int kb0 = kt * 64 + n * 16 + lq * 4;
                    #pragma unroll
                    for (int r = 0; r < 4; ++r)
                        lacc[n] += (kb0 + r <= myq) ? exp2f(s[n][r] * SC) : 0.f;
                }
            } else {
                #pragma unroll
                for (int n = 0; n < 4; ++n)
                    #pragma unroll
                    for (int r = 0; r < 4; ++r)
                        lacc[n] += exp2f(s[n][r] * SC);
            }
        }
        LGKM_BARRIER();
    }
    float lsum = (lacc[0] + lacc[1]) + (lacc[2] + lacc[3]);
    lsum += __shfl_xor(lsum, 16);
    lsum += __shfl_xor(lsum, 32);
    const float linv = 1.f / lsum;

    // ---- phase 2: recompute S, NT weight stores, P@V; reg-staged K/V ----
    short* Ks2 = lds;                       // [2][64*72]
    short* Vs2 = lds + 2 * 64 * 72;         // [2][64*72]
    short* Psw = lds + 4 * 64 * 72 + wid * (16 * 72);

    bf16x8 krg0, krg1, vrg0, vrg1;          // staged tile (named: rule #20)
    auto loadKV = [&](int kt) {
        krg0 = *(const bf16x8*)&kbase[(size_t)(kt * 64 + srow) * DM + scol];
        krg1 = *(const bf16x8*)&kbase[(size_t)(kt * 64 + srow + 32) * DM + scol];
        vrg0 = *(const bf16x8*)&vbase[(size_t)srow * TSEQ + kt * 64 + scol];
        vrg1 = *(const bf16x8*)&vbase[(size_t)(srow + 32) * TSEQ + kt * 64 + scol];
    };
    auto writeKV = [&](int b) {
        short* kd = Ks2 + b * (64 * 72);
        short* vd = Vs2 + b * (64 * 72);
        *(bf16x8*)&kd[srow * 72 + scol] = krg0;
        *(bf16x8*)&kd[(srow + 32) * 72 + scol] = krg1;
        *(bf16x8*)&vd[srow * 72 + scol] = vrg0;
        *(bf16x8*)&vd[(srow + 32) * 72 + scol] = vrg1;
    };

    float* wq = Wout + (size_t)h * TSEQ * TSEQ + (size_t)myq * TSEQ;
    f32x4 o[4] = {};
    loadKV(0);
    writeKV(0);
    LGKM_BARRIER();
    for (int kt = 0; kt < nkt; ++kt) {
        const int b = kt & 1;
        const bool more = (kt + 1 < nkt);
        if (more) {
            loadKV(kt + 1);                       // issue loads early
            __builtin_amdgcn_sched_barrier(0);    // pin: loads above compute
        }
        f32x4 s[4] = {};
        __builtin_amdgcn_s_setprio(1);
        #pragma unroll
        for (int ks = 0; ks < 2; ++ks) {
            bf16x8 qf = ks ? qf1 : qf0;
            #pragma unroll
            for (int n = 0; n < 4; ++n) {
                bf16x8 kf = *(const bf16x8*)
                    &Ks2[b * (64 * 72) + (n * 16 + l15) * 72 + ks * 32 + lq * 8];
                s[n] = mfma16(kf, qf, s[n]);
            }
        }
        __builtin_amdgcn_s_setprio(0);
        const bool diag = (kt == qt);
        #pragma unroll
        for (int n = 0; n < 4; ++n) {
            const int kb0 = kt * 64 + n * 16 + lq * 4;
            f32x4 p;
            #pragma unroll
            for (int r = 0; r < 4; ++r) {
                float e = exp2f(s[n][r] * SC) * linv;
                p[r] = (diag && (kb0 + r > myq)) ? 0.f : e;
            }
            __builtin_nontemporal_store(p, (f32x4*)(wq + kb0));  // exact fp32
            bf16x4 pb;
            #pragma unroll
            for (int r = 0; r < 4; ++r) pb[r] = f2bf(p[r]);
            *(bf16x4*)&Psw[l15 * 72 + n * 16 + lq * 4] = pb;
        }
        // P @ V: A-frag = P (q rows) from per-wave Ps, B-frag = V^T from LDS
        __builtin_amdgcn_s_setprio(1);
        #pragma unroll
        for (int ks = 0; ks < 2; ++ks) {
            bf16x8 pf = *(bf16x8*)&Psw[l15 * 72 + ks * 32 + lq * 8];
            #pragma unroll
            for (int n = 0; n < 4; ++n) {
                bf16x8 vf = *(const bf16x8*)
                    &Vs2[b * (64 * 72) + (n * 16 + l15) * 72 + ks * 32 + lq * 8];
                o[n] = mfma16(pf, vf, o[n]);
            }
        }
        __builtin_amdgcn_s_setprio(0);
        if (more) {
            __builtin_amdgcn_sched_barrier(0);    // pin: ds_write after stores
            writeKV(b ^ 1);                       // reg -> LDS, no vmcnt(0)
        }
        LGKM_BARRIER();
    }

    // ---- epilogue: O (row = q0+wid*16+lq*4+r, col = h*64+n*16+l15) ----
    #pragma unroll
    for (int n = 0; n < 4; ++n) {
        int col = h * HDIM + n * 16 + l15;
        #pragma unroll
        for (int r = 0; r < 4; ++r) {
            int row = q0 + wid * 16 + lq * 4 + r;
            AttnO[(size_t)row * DM + col] = o[n][r];
        }
    }
}

extern "C" void kernel_launch(void* const* d_in, const int* in_sizes, int n_in,
                              void* d_out, int out_size, void* d_ws, size_t ws_size,
                              hipStream_t stream)
{
    const float* q_in = (const float*)d_in[0];
    const float* k_in = (const float*)d_in[1];
    const float* v_in = (const float*)d_in[2];
    // d_in[3] = causal mask (triu, k=1) — structure known, not read
    const float* Wq_w = (const float*)d_in[4];
    const float* Wq_b = (const float*)d_in[5];
    const float* Wk_w = (const float*)d_in[6];
    const float* Wk_b = (const float*)d_in[7];
    const float* Wv_w = (const float*)d_in[8];
    const float* Wv_b = (const float*)d_in[9];
    const float* W0_w = (const float*)d_in[10];
    const float* W0_b = (const float*)d_in[11];

    float* out  = (float*)d_out;                       // [4096][768] fp32
    float* wout = out + (size_t)TSEQ * DM;             // [12][4096][4096] fp32

    short* Qb = (short*)d_ws;                          // [4096][768] bf16
    short* Kb = Qb + (size_t)TSEQ * DM;                // [4096][768] bf16
    short* Vt = Kb + (size_t)TSEQ * DM;                // [768][4096] bf16 (V^T)
    float* AttnO = (float*)(Vt + (size_t)TSEQ * DM);   // [4096][768] fp32

    gemm_qkv<<<dim3(TSEQ / 64, DM / 64, 3), 256, 0, stream>>>(
        q_in, k_in, v_in, Wq_w, Wq_b, Wk_w, Wk_b, Wv_w, Wv_b, Qb, Kb, Vt);
    attn_fused<<<dim3(64, NHEAD), 256, 0, stream>>>(Qb, Kb, Vt, wout, AttnO);
    gemm_out<<<dim3(TSEQ / 64, DM / 64), 256, 0, stream>>>(AttnO, W0_w, W0_b, out);
}

// Round 6
// 335.303 us; speedup vs baseline: 2.0932x; 1.0221x over previous
//
#include <hip/hip_runtime.h>

#define TSEQ 4096
#define DM 768
#define NHEAD 12
#define HDIM 64
#define SC 0.1803368801111204f  // (1/sqrt(64)) * log2(e)

using f32x4  = __attribute__((ext_vector_type(4))) float;
using bf16x8 = __attribute__((ext_vector_type(8))) short;
using bf16x4 = __attribute__((ext_vector_type(4))) short;

// Barrier that waits only LDS ops — global stores stay in flight (no vmcnt(0)
// drain; the T4 "never vmcnt(0) in the main loop" rule).
#define LGKM_BARRIER() asm volatile("s_waitcnt lgkmcnt(0)\n\ts_barrier" ::: "memory")

__device__ __forceinline__ short f2bf(float f) {
    union { float f; unsigned u; } x; x.f = f;
    unsigned r = x.u + 0x7FFFu + ((x.u >> 16) & 1u);  // RNE; inputs finite
    return (short)(r >> 16);
}

// hardware packed f32x2 -> bf16x2 (RNE), 1 inst for 2 conversions
__device__ __forceinline__ unsigned pk2(float lo, float hi) {
    unsigned d;
    asm("v_cvt_pk_bf16_f32 %0, %1, %2" : "=v"(d) : "v"(lo), "v"(hi));
    return d;
}

__device__ __forceinline__ bf16x8 pack8(f32x4 a, f32x4 b) {
    union { unsigned u[4]; bf16x8 v; } r;
    r.u[0] = pk2(a[0], a[1]); r.u[1] = pk2(a[2], a[3]);
    r.u[2] = pk2(b[0], b[1]); r.u[3] = pk2(b[2], b[3]);
    return r.v;
}

__device__ __forceinline__ f32x4 mfma16(bf16x8 a, bf16x8 b, f32x4 c) {
    return __builtin_amdgcn_mfma_f32_16x16x32_bf16(a, b, c, 0, 0, 0);
}

// ---------------- fused QKV projection GEMMs (one dispatch, grid.z=3) --------
// C = A(4096x768) @ W(768x768)^T + bias. Tile 64x64, BK=64, 4 waves.
// z=0: Q -> bf16 row-major; z=1: K -> bf16 row-major; z=2: V -> bf16 transposed.
__global__ __launch_bounds__(256) void gemm_qkv(
    const float* __restrict__ q_in, const float* __restrict__ k_in,
    const float* __restrict__ v_in,
    const float* __restrict__ Wq_w, const float* __restrict__ Wq_b,
    const float* __restrict__ Wk_w, const float* __restrict__ Wk_b,
    const float* __restrict__ Wv_w, const float* __restrict__ Wv_b,
    short* __restrict__ Qb, short* __restrict__ Kb, short* __restrict__ Vt)
{
    constexpr int K = DM;
    __shared__ __align__(16) short As[64 * 72];
    __shared__ __align__(16) short Bs[64 * 72];
    const int z = blockIdx.z;
    const float* A    = (z == 0) ? q_in : (z == 1) ? k_in : v_in;
    const float* W    = (z == 0) ? Wq_w : (z == 1) ? Wk_w : Wv_w;
    const float* bias = (z == 0) ? Wq_b : (z == 1) ? Wk_b : Wv_b;

    const int bm = blockIdx.x * 64;
    const int bn = blockIdx.y * 64;
    const int tid = threadIdx.x;
    const int wid = tid >> 6;
    const int lane = tid & 63;
    const int l15 = lane & 15, lq = lane >> 4;

    f32x4 acc[4] = {};
    const int sr = tid >> 3;
    const int sc = (tid & 7) * 8;

    for (int k0 = 0; k0 < K; k0 += 64) {
        #pragma unroll
        for (int it = 0; it < 2; ++it) {
            int r = sr + it * 32;
            const float* ga = A + (size_t)(bm + r) * K + k0 + sc;
            f32x4 a0 = *(const f32x4*)ga;
            f32x4 a1 = *(const f32x4*)(ga + 4);
            *(bf16x8*)&As[r * 72 + sc] = pack8(a0, a1);
            const float* gb = W + (size_t)(bn + r) * K + k0 + sc;
            f32x4 b0 = *(const f32x4*)gb;
            f32x4 b1 = *(const f32x4*)(gb + 4);
            *(bf16x8*)&Bs[r * 72 + sc] = pack8(b0, b1);
        }
        LGKM_BARRIER();
        __builtin_amdgcn_s_setprio(1);
        #pragma unroll
        for (int ks = 0; ks < 2; ++ks) {
            bf16x8 af = *(bf16x8*)&As[(wid * 16 + l15) * 72 + ks * 32 + lq * 8];
            #pragma unroll
            for (int n = 0; n < 4; ++n) {
                bf16x8 bfv = *(bf16x8*)&Bs[(n * 16 + l15) * 72 + ks * 32 + lq * 8];
                acc[n] = mfma16(af, bfv, acc[n]);
            }
        }
        __builtin_amdgcn_s_setprio(0);
        LGKM_BARRIER();
    }

    const int row0 = bm + wid * 16 + lq * 4;
    #pragma unroll
    for (int n = 0; n < 4; ++n) {
        int col = bn + n * 16 + l15;
        float b = bias[col];
        if (z == 2) {  // V transposed [768][4096]
            uint2 pv;
            pv.x = pk2(acc[n][0] + b, acc[n][1] + b);
            pv.y = pk2(acc[n][2] + b, acc[n][3] + b);
            *(uint2*)(Vt + (size_t)col * TSEQ + row0) = pv;
        } else {
            short* dst = (z == 0) ? Qb : Kb;
            #pragma unroll
            for (int r = 0; r < 4; ++r)
                dst[(size_t)(row0 + r) * DM + col] = f2bf(acc[n][r] + b);
        }
    }
}

// ---------------- output GEMM: out = AttnO(4096x768) @ W0^T + b0 (fp32) ------
__global__ __launch_bounds__(256) void gemm_out(
    const float* __restrict__ A, const float* __restrict__ W,
    const float* __restrict__ bias, float* __restrict__ Cout)
{
    constexpr int K = DM;
    __shared__ __align__(16) short As[64 * 72];
    __shared__ __align__(16) short Bs[64 * 72];
    const int bm = blockIdx.x * 64;
    const int bn = blockIdx.y * 64;
    const int tid = threadIdx.x;
    const int wid = tid >> 6;
    const int lane = tid & 63;
    const int l15 = lane & 15, lq = lane >> 4;

    f32x4 acc[4] = {};
    const int sr = tid >> 3;
    const int sc = (tid & 7) * 8;

    for (int k0 = 0; k0 < K; k0 += 64) {
        #pragma unroll
        for (int it = 0; it < 2; ++it) {
            int r = sr + it * 32;
            const float* ga = A + (size_t)(bm + r) * K + k0 + sc;
            f32x4 a0 = *(const f32x4*)ga;
            f32x4 a1 = *(const f32x4*)(ga + 4);
            *(bf16x8*)&As[r * 72 + sc] = pack8(a0, a1);
            const float* gb = W + (size_t)(bn + r) * K + k0 + sc;
            f32x4 b0 = *(const f32x4*)gb;
            f32x4 b1 = *(const f32x4*)(gb + 4);
            *(bf16x8*)&Bs[r * 72 + sc] = pack8(b0, b1);
        }
        LGKM_BARRIER();
        __builtin_amdgcn_s_setprio(1);
        #pragma unroll
        for (int ks = 0; ks < 2; ++ks) {
            bf16x8 af = *(bf16x8*)&As[(wid * 16 + l15) * 72 + ks * 32 + lq * 8];
            #pragma unroll
            for (int n = 0; n < 4; ++n) {
                bf16x8 bfv = *(bf16x8*)&Bs[(n * 16 + l15) * 72 + ks * 32 + lq * 8];
                acc[n] = mfma16(af, bfv, acc[n]);
            }
        }
        __builtin_amdgcn_s_setprio(0);
        LGKM_BARRIER();
    }

    const int row0 = bm + wid * 16 + lq * 4;
    #pragma unroll
    for (int n = 0; n < 4; ++n) {
        int col = bn + n * 16 + l15;
        float b = bias[col];
        #pragma unroll
        for (int r = 0; r < 4; ++r)
            Cout[(size_t)(row0 + r) * DM + col] = acc[n][r] + b;
    }
}

// ---------------- fused causal attention ----------------
// grid (64 q-tiles heavy-first, 12 heads), 256 threads (4 waves, 16 q-rows).
// Swapped QK^T (mfma(K,Q)): thread owns q-row = lane&15, k = n*16+lq*4+r.
// Phase 1: exp row-sums, K staged in 128-row LDS chunks.
// Phase 2: recompute S; p = exp2(fma(s,SC,-log2(lsum))) -> plain f32x4 weight
// stores (L2 write-combining) + cvt_pk bf16 packing for the PV A-frag.
// K/V reg-staged (async split) into double-buffered LDS; lgkm-only barriers.
__global__ __launch_bounds__(256) void attn_fused(
    const short* __restrict__ Qb, const short* __restrict__ Kb,
    const short* __restrict__ Vt, float* __restrict__ Wout,
    float* __restrict__ AttnO)
{
    const int qt = 63 - blockIdx.x;     // heavy blocks first
    const int h = blockIdx.y;
    const int q0 = qt * 64;
    const int tid = threadIdx.x, wid = tid >> 6, lane = tid & 63;
    const int l15 = lane & 15, lq = lane >> 4;

    // one pool, aliased: phase1 K-chunks [2][128*72]=36864B;
    // phase2 Ks[2][64*72]+Vs[2][64*72]+Ps[4][16*72]=46080B
    __shared__ __align__(16) short lds[23040];

    const int nkt = qt + 1;

    // ---- zero strict-upper tail (NT stores: pure streaming, fire-and-forget) ----
    {
        float* wbase = Wout + (size_t)h * TSEQ * TSEQ + (size_t)(q0 + wid * 16) * TSEQ;
        f32x4 z = {0.f, 0.f, 0.f, 0.f};
        for (int kt = nkt; kt < 64; ++kt) {
            #pragma unroll
            for (int i = 0; i < 4; ++i)
                __builtin_nontemporal_store(
                    z, (f32x4*)(wbase + (size_t)(lq + i * 4) * TSEQ + kt * 64 + l15 * 4));
        }
    }

    // Q as MFMA B-operand: q-row = lane&15, k = (lane>>4)*8
    const short* qp = Qb + (size_t)(q0 + wid * 16 + l15) * DM + h * HDIM + lq * 8;
    bf16x8 qf0 = *(const bf16x8*)qp;
    bf16x8 qf1 = *(const bf16x8*)(qp + 32);

    const short* kbase = Kb + (size_t)h * HDIM;        // + k_row * DM
    const short* vbase = Vt + (size_t)h * HDIM * TSEQ; // + hd_row * TSEQ
    const int myq = q0 + wid * 16 + l15;

    const int srow = tid >> 3;          // 0..31
    const int scol = (tid & 7) * 8;     // 0..56

    // ---- phase 1: row sums of exp; K staged in 128-row chunks ----
    const int nch = (nkt + 1) >> 1;
    auto stageKbig = [&](int c, int b) {
        const int base_k = c * 128;
        const int iters = (nkt * 64 - base_k) >= 128 ? 4 : 2;
        short* dst = lds + b * (128 * 72);
        for (int it = 0; it < iters; ++it) {
            int r = srow + it * 32;
            *(bf16x8*)&dst[r * 72 + scol] =
                *(const bf16x8*)&kbase[(size_t)(base_k + r) * DM + scol];
        }
    };

    f32x4 lacc = {0.f, 0.f, 0.f, 0.f};
    stageKbig(0, 0);
    LGKM_BARRIER();
    for (int c = 0; c < nch; ++c) {
        const int b = c & 1;
        if (c + 1 < nch) stageKbig(c + 1, b ^ 1);
        const short* kb = lds + b * (128 * 72);
        #pragma unroll
        for (int t = 0; t < 2; ++t) {
            const int kt = c * 2 + t;
            if (kt >= nkt) break;
            f32x4 s[4] = {};
            __builtin_amdgcn_s_setprio(1);
            #pragma unroll
            for (int ks = 0; ks < 2; ++ks) {
                bf16x8 qf = ks ? qf1 : qf0;
                #pragma unroll
                for (int n = 0; n < 4; ++n) {
                    bf16x8 kf = *(const bf16x8*)
                        &kb[(t * 64 + n * 16 + l15) * 72 + ks * 32 + lq * 8];
                    s[n] = mfma16(kf, qf, s[n]);
                }
            }
            __builtin_amdgcn_s_setprio(0);
            if (kt == qt) {  // diagonal: mask k > q
                #pragma unroll
                for (int n = 0; n < 4; ++n) {
                    int kb0 = kt * 64 + n * 16 + lq * 4;
                    #pragma unroll
                    for (int r = 0; r < 4; ++r)
                        lacc[n] += (kb0 + r <= myq) ? exp2f(s[n][r] * SC) : 0.f;
                }
            } else {
                #pragma unroll
                for (int n = 0; n < 4; ++n)
                    #pragma unroll
                    for (int r = 0; r < 4; ++r)
                        lacc[n] += exp2f(s[n][r] * SC);
            }
        }
        LGKM_BARRIER();
    }
    float lsum = (lacc[0] + lacc[1]) + (lacc[2] + lacc[3]);
    lsum += __shfl_xor(lsum, 16);
    lsum += __shfl_xor(lsum, 32);
    const float nlog = -__log2f(lsum);   // fold 1/lsum into the exponent

    // ---- phase 2: recompute S, weight stores, P@V; reg-staged K/V ----
    short* Ks2 = lds;                       // [2][64*72]
    short* Vs2 = lds + 2 * 64 * 72;         // [2][64*72]
    short* Psw = lds + 4 * 64 * 72 + wid * (16 * 72);

    bf16x8 krg0, krg1, vrg0, vrg1;          // staged tile (named: rule #20)
    auto loadKV = [&](int kt) {
        krg0 = *(const bf16x8*)&kbase[(size_t)(kt * 64 + srow) * DM + scol];
        krg1 = *(const bf16x8*)&kbase[(size_t)(kt * 64 + srow + 32) * DM + scol];
        vrg0 = *(const bf16x8*)&vbase[(size_t)srow * TSEQ + kt * 64 + scol];
        vrg1 = *(const bf16x8*)&vbase[(size_t)(srow + 32) * TSEQ + kt * 64 + scol];
    };
    auto writeKV = [&](int b) {
        short* kd = Ks2 + b * (64 * 72);
        short* vd = Vs2 + b * (64 * 72);
        *(bf16x8*)&kd[srow * 72 + scol] = krg0;
        *(bf16x8*)&kd[(srow + 32) * 72 + scol] = krg1;
        *(bf16x8*)&vd[srow * 72 + scol] = vrg0;
        *(bf16x8*)&vd[(srow + 32) * 72 + scol] = vrg1;
    };

    float* wq = Wout + (size_t)h * TSEQ * TSEQ + (size_t)myq * TSEQ;
    f32x4 o[4] = {};
    loadKV(0);
    writeKV(0);
    LGKM_BARRIER();
    for (int kt = 0; kt < nkt; ++kt) {
        const int b = kt & 1;
        const bool more = (kt + 1 < nkt);
        if (more) {
            loadKV(kt + 1);                       // issue loads early
            __builtin_amdgcn_sched_barrier(0);    // pin: loads above compute
        }
        f32x4 s[4] = {};
        __builtin_amdgcn_s_setprio(1);
        #pragma unroll
        for (int ks = 0; ks < 2; ++ks) {
            bf16x8 qf = ks ? qf1 : qf0;
            #pragma unroll
            for (int n = 0; n < 4; ++n) {
                bf16x8 kf = *(const bf16x8*)
                    &Ks2[b * (64 * 72) + (n * 16 + l15) * 72 + ks * 32 + lq * 8];
                s[n] = mfma16(kf, qf, s[n]);
            }
        }
        __builtin_amdgcn_s_setprio(0);
        const bool diag = (kt == qt);
        #pragma unroll
        for (int n = 0; n < 4; ++n) {
            const int kb0 = kt * 64 + n * 16 + lq * 4;
            f32x4 p;
            #pragma unroll
            for (int r = 0; r < 4; ++r) {
                float e = exp2f(fmaf(s[n][r], SC, nlog));  // normalized
                p[r] = (diag && (kb0 + r > myq)) ? 0.f : e;
            }
            *(f32x4*)(wq + kb0) = p;              // plain store: L2-merged
            uint2 pv;
            pv.x = pk2(p[0], p[1]);
            pv.y = pk2(p[2], p[3]);
            *(uint2*)&Psw[l15 * 72 + n * 16 + lq * 4] = pv;
        }
        // P @ V: A-frag = P (q rows) from per-wave Ps, B-frag = V^T from LDS
        __builtin_amdgcn_s_setprio(1);
        #pragma unroll
        for (int ks = 0; ks < 2; ++ks) {
            bf16x8 pf = *(bf16x8*)&Psw[l15 * 72 + ks * 32 + lq * 8];
            #pragma unroll
            for (int n = 0; n < 4; ++n) {
                bf16x8 vf = *(const bf16x8*)
                    &Vs2[b * (64 * 72) + (n * 16 + l15) * 72 + ks * 32 + lq * 8];
                o[n] = mfma16(pf, vf, o[n]);
            }
        }
        __builtin_amdgcn_s_setprio(0);
        if (more) {
            __builtin_amdgcn_sched_barrier(0);    // pin: ds_write after stores
            writeKV(b ^ 1);                       // reg -> LDS, no vmcnt(0)
        }
        LGKM_BARRIER();
    }

    // ---- epilogue: O (row = q0+wid*16+lq*4+r, col = h*64+n*16+l15) ----
    #pragma unroll
    for (int n = 0; n < 4; ++n) {
        int col = h * HDIM + n * 16 + l15;
        #pragma unroll
        for (int r = 0; r < 4; ++r) {
            int row = q0 + wid * 16 + lq * 4 + r;
            AttnO[(size_t)row * DM + col] = o[n][r];
        }
    }
}

extern "C" void kernel_launch(void* const* d_in, const int* in_sizes, int n_in,
                              void* d_out, int out_size, void* d_ws, size_t ws_size,
                              hipStream_t stream)
{
    const float* q_in = (const float*)d_in[0];
    const float* k_in = (const float*)d_in[1];
    const float* v_in = (const float*)d_in[2];
    // d_in[3] = causal mask (triu, k=1) — structure known, not read
    const float* Wq_w = (const float*)d_in[4];
    const float* Wq_b = (const float*)d_in[5];
    const float* Wk_w = (const float*)d_in[6];
    const float* Wk_b = (const float*)d_in[7];
    const float* Wv_w = (const float*)d_in[8];
    const float* Wv_b = (const float*)d_in[9];
    const float* W0_w = (const float*)d_in[10];
    const float* W0_b = (const float*)d_in[11];

    float* out  = (float*)d_out;                       // [4096][768] fp32
    float* wout = out + (size_t)TSEQ * DM;             // [12][4096][4096] fp32

    short* Qb = (short*)d_ws;                          // [4096][768] bf16
    short* Kb = Qb + (size_t)TSEQ * DM;                // [4096][768] bf16
    short* Vt = Kb + (size_t)TSEQ * DM;                // [768][4096] bf16 (V^T)
    float* AttnO = (float*)(Vt + (size_t)TSEQ * DM);   // [4096][768] fp32

    gemm_qkv<<<dim3(TSEQ / 64, DM / 64, 3), 256, 0, stream>>>(
        q_in, k_in, v_in, Wq_w, Wq_b, Wk_w, Wk_b, Wv_w, Wv_b, Qb, Kb, Vt);
    attn_fused<<<dim3(64, NHEAD), 256, 0, stream>>>(Qb, Kb, Vt, wout, AttnO);
    gemm_out<<<dim3(TSEQ / 64, DM / 64), 256, 0, stream>>>(AttnO, W0_w, W0_b, out);
}

// Round 7
// 319.066 us; speedup vs baseline: 2.1998x; 1.0509x over previous
//
#include <hip/hip_runtime.h>

#define TSEQ 4096
#define DM 768
#define NHEAD 12
#define HDIM 64
#define SC 0.1803368801111204f  // (1/sqrt(64)) * log2(e)

using f32x4  = __attribute__((ext_vector_type(4))) float;
using bf16x8 = __attribute__((ext_vector_type(8))) short;
using bf16x4 = __attribute__((ext_vector_type(4))) short;

// Barrier that waits only LDS ops — global stores stay in flight (no vmcnt(0)
// drain; the T4 "never vmcnt(0) in the main loop" rule).
#define LGKM_BARRIER() asm volatile("s_waitcnt lgkmcnt(0)\n\ts_barrier" ::: "memory")

__device__ __forceinline__ short f2bf(float f) {
    union { float f; unsigned u; } x; x.f = f;
    unsigned r = x.u + 0x7FFFu + ((x.u >> 16) & 1u);  // RNE; inputs finite
    return (short)(r >> 16);
}

// hardware packed f32x2 -> bf16x2 (RNE), 1 inst for 2 conversions
__device__ __forceinline__ unsigned pk2(float lo, float hi) {
    unsigned d;
    asm("v_cvt_pk_bf16_f32 %0, %1, %2" : "=v"(d) : "v"(lo), "v"(hi));
    return d;
}

__device__ __forceinline__ bf16x8 pack8(f32x4 a, f32x4 b) {
    union { unsigned u[4]; bf16x8 v; } r;
    r.u[0] = pk2(a[0], a[1]); r.u[1] = pk2(a[2], a[3]);
    r.u[2] = pk2(b[0], b[1]); r.u[3] = pk2(b[2], b[3]);
    return r.v;
}

__device__ __forceinline__ f32x4 mfma16(bf16x8 a, bf16x8 b, f32x4 c) {
    return __builtin_amdgcn_mfma_f32_16x16x32_bf16(a, b, c, 0, 0, 0);
}

// ---------------- fused QKV projection GEMMs ----------------
// C = A(4096x768) @ W(768x768)^T + bias. Tile 64x256, BK=64, 512 thr (8 waves,
// 2M x 4N). Flat grid 576; dispatch order: bm fastest within (bn,z) so the 64
// blocks sharing a W-tile (786KB, L2-fits) run together; XCD swizzle keeps a
// W-group on ~1 XCD. A is streamed (no intra-group reuse): fetch = 3 bn x
// 12.6MB x 3 inputs ~ 113MB (was ~450MB at BN=64).
// z=0: Q -> bf16 row-major; z=1: K -> bf16 row-major; z=2: V -> bf16 transposed.
__global__ __launch_bounds__(512) void gemm_qkv(
    const float* __restrict__ q_in, const float* __restrict__ k_in,
    const float* __restrict__ v_in,
    const float* __restrict__ Wq_w, const float* __restrict__ Wq_b,
    const float* __restrict__ Wk_w, const float* __restrict__ Wk_b,
    const float* __restrict__ Wv_w, const float* __restrict__ Wv_b,
    short* __restrict__ Qb, short* __restrict__ Kb, short* __restrict__ Vt)
{
    constexpr int K = DM;
    __shared__ __align__(16) short As[64 * 72];    // 9.2 KB
    __shared__ __align__(16) short Bs[256 * 72];   // 36.9 KB

    // XCD-chunked bijective swizzle: 576 blocks, 72 per XCD
    const int D = blockIdx.x;
    const int o = (D & 7) * 72 + (D >> 3);
    const int bm = (o & 63) * 64;
    const int g  = o >> 6;             // 0..8 = (bn, z)
    const int bn = (g % 3) * 256;
    const int z  = g / 3;

    const float* A    = (z == 0) ? q_in : (z == 1) ? k_in : v_in;
    const float* W    = (z == 0) ? Wq_w : (z == 1) ? Wk_w : Wv_w;
    const float* bias = (z == 0) ? Wq_b : (z == 1) ? Wk_b : Wv_b;

    const int tid = threadIdx.x;
    const int wid = tid >> 6;
    const int lane = tid & 63;
    const int wm = wid >> 2, wn = wid & 3;
    const int l15 = lane & 15, lq = lane >> 4;

    f32x4 acc[2][4] = {};
    const int sr = tid >> 3;        // 0..63
    const int sc = (tid & 7) * 8;   // 0..56

    for (int k0 = 0; k0 < K; k0 += 64) {
        {   // A tile: 64 rows x 64 k
            const float* ga = A + (size_t)(bm + sr) * K + k0 + sc;
            *(bf16x8*)&As[sr * 72 + sc] =
                pack8(*(const f32x4*)ga, *(const f32x4*)(ga + 4));
        }
        #pragma unroll
        for (int it = 0; it < 4; ++it) {  // W tile: 256 rows x 64 k
            int r = sr + it * 64;
            const float* gb = W + (size_t)(bn + r) * K + k0 + sc;
            *(bf16x8*)&Bs[r * 72 + sc] =
                pack8(*(const f32x4*)gb, *(const f32x4*)(gb + 4));
        }
        LGKM_BARRIER();
        __builtin_amdgcn_s_setprio(1);
        #pragma unroll
        for (int ks = 0; ks < 2; ++ks) {
            bf16x8 af0 = *(bf16x8*)&As[(wm * 32 + l15) * 72 + ks * 32 + lq * 8];
            bf16x8 af1 = *(bf16x8*)&As[(wm * 32 + 16 + l15) * 72 + ks * 32 + lq * 8];
            #pragma unroll
            for (int n = 0; n < 4; ++n) {
                bf16x8 bfv = *(bf16x8*)&Bs[(wn * 64 + n * 16 + l15) * 72 + ks * 32 + lq * 8];
                acc[0][n] = mfma16(af0, bfv, acc[0][n]);
                acc[1][n] = mfma16(af1, bfv, acc[1][n]);
            }
        }
        __builtin_amdgcn_s_setprio(0);
        LGKM_BARRIER();
    }

    // C/D layout: col = lane&15 (N), row = (lane>>4)*4 + reg (M)
    #pragma unroll
    for (int mf = 0; mf < 2; ++mf) {
        const int row0 = bm + wm * 32 + mf * 16 + lq * 4;
        #pragma unroll
        for (int n = 0; n < 4; ++n) {
            int col = bn + wn * 64 + n * 16 + l15;
            float b = bias[col];
            if (z == 2) {  // V transposed [768][4096]
                uint2 pv;
                pv.x = pk2(acc[mf][n][0] + b, acc[mf][n][1] + b);
                pv.y = pk2(acc[mf][n][2] + b, acc[mf][n][3] + b);
                *(uint2*)(Vt + (size_t)col * TSEQ + row0) = pv;
            } else {
                short* dst = (z == 0) ? Qb : Kb;
                #pragma unroll
                for (int r = 0; r < 4; ++r)
                    dst[(size_t)(row0 + r) * DM + col] = f2bf(acc[mf][n][r] + b);
            }
        }
    }
}

// ---------------- output GEMM: out = AttnO(4096x768) @ W0^T + b0 (fp32) ------
// Same 64x256 structure; 192 blocks, 24 per XCD.
__global__ __launch_bounds__(512) void gemm_out(
    const float* __restrict__ A, const float* __restrict__ W,
    const float* __restrict__ bias, float* __restrict__ Cout)
{
    constexpr int K = DM;
    __shared__ __align__(16) short As[64 * 72];
    __shared__ __align__(16) short Bs[256 * 72];

    const int D = blockIdx.x;
    const int o = (D & 7) * 24 + (D >> 3);
    const int bm = (o & 63) * 64;
    const int bn = (o >> 6) * 256;

    const int tid = threadIdx.x;
    const int wid = tid >> 6;
    const int lane = tid & 63;
    const int wm = wid >> 2, wn = wid & 3;
    const int l15 = lane & 15, lq = lane >> 4;

    f32x4 acc[2][4] = {};
    const int sr = tid >> 3;
    const int sc = (tid & 7) * 8;

    for (int k0 = 0; k0 < K; k0 += 64) {
        {
            const float* ga = A + (size_t)(bm + sr) * K + k0 + sc;
            *(bf16x8*)&As[sr * 72 + sc] =
                pack8(*(const f32x4*)ga, *(const f32x4*)(ga + 4));
        }
        #pragma unroll
        for (int it = 0; it < 4; ++it) {
            int r = sr + it * 64;
            const float* gb = W + (size_t)(bn + r) * K + k0 + sc;
            *(bf16x8*)&Bs[r * 72 + sc] =
                pack8(*(const f32x4*)gb, *(const f32x4*)(gb + 4));
        }
        LGKM_BARRIER();
        __builtin_amdgcn_s_setprio(1);
        #pragma unroll
        for (int ks = 0; ks < 2; ++ks) {
            bf16x8 af0 = *(bf16x8*)&As[(wm * 32 + l15) * 72 + ks * 32 + lq * 8];
            bf16x8 af1 = *(bf16x8*)&As[(wm * 32 + 16 + l15) * 72 + ks * 32 + lq * 8];
            #pragma unroll
            for (int n = 0; n < 4; ++n) {
                bf16x8 bfv = *(bf16x8*)&Bs[(wn * 64 + n * 16 + l15) * 72 + ks * 32 + lq * 8];
                acc[0][n] = mfma16(af0, bfv, acc[0][n]);
                acc[1][n] = mfma16(af1, bfv, acc[1][n]);
            }
        }
        __builtin_amdgcn_s_setprio(0);
        LGKM_BARRIER();
    }

    #pragma unroll
    for (int mf = 0; mf < 2; ++mf) {
        const int row0 = bm + wm * 32 + mf * 16 + lq * 4;
        #pragma unroll
        for (int n = 0; n < 4; ++n) {
            int col = bn + wn * 64 + n * 16 + l15;
            float b = bias[col];
            #pragma unroll
            for (int r = 0; r < 4; ++r)
                Cout[(size_t)(row0 + r) * DM + col] = acc[mf][n][r] + b;
        }
    }
}

// ---------------- fused causal attention (unchanged from round 6) ----------
__global__ __launch_bounds__(256) void attn_fused(
    const short* __restrict__ Qb, const short* __restrict__ Kb,
    const short* __restrict__ Vt, float* __restrict__ Wout,
    float* __restrict__ AttnO)
{
    const int qt = 63 - blockIdx.x;     // heavy blocks first
    const int h = blockIdx.y;
    const int q0 = qt * 64;
    const int tid = threadIdx.x, wid = tid >> 6, lane = tid & 63;
    const int l15 = lane & 15, lq = lane >> 4;

    // one pool, aliased: phase1 K-chunks [2][128*72]=36864B;
    // phase2 Ks[2][64*72]+Vs[2][64*72]+Ps[4][16*72]=46080B
    __shared__ __align__(16) short lds[23040];

    const int nkt = qt + 1;

    // ---- zero strict-upper tail (NT stores: pure streaming) ----
    {
        float* wbase = Wout + (size_t)h * TSEQ * TSEQ + (size_t)(q0 + wid * 16) * TSEQ;
        f32x4 z = {0.f, 0.f, 0.f, 0.f};
        for (int kt = nkt; kt < 64; ++kt) {
            #pragma unroll
            for (int i = 0; i < 4; ++i)
                __builtin_nontemporal_store(
                    z, (f32x4*)(wbase + (size_t)(lq + i * 4) * TSEQ + kt * 64 + l15 * 4));
        }
    }

    // Q as MFMA B-operand: q-row = lane&15, k = (lane>>4)*8
    const short* qp = Qb + (size_t)(q0 + wid * 16 + l15) * DM + h * HDIM + lq * 8;
    bf16x8 qf0 = *(const bf16x8*)qp;
    bf16x8 qf1 = *(const bf16x8*)(qp + 32);

    const short* kbase = Kb + (size_t)h * HDIM;        // + k_row * DM
    const short* vbase = Vt + (size_t)h * HDIM * TSEQ; // + hd_row * TSEQ
    const int myq = q0 + wid * 16 + l15;

    const int srow = tid >> 3;          // 0..31
    const int scol = (tid & 7) * 8;     // 0..56

    // ---- phase 1: row sums of exp; K staged in 128-row chunks ----
    const int nch = (nkt + 1) >> 1;
    auto stageKbig = [&](int c, int b) {
        const int base_k = c * 128;
        const int iters = (nkt * 64 - base_k) >= 128 ? 4 : 2;
        short* dst = lds + b * (128 * 72);
        for (int it = 0; it < iters; ++it) {
            int r = srow + it * 32;
            *(bf16x8*)&dst[r * 72 + scol] =
                *(const bf16x8*)&kbase[(size_t)(base_k + r) * DM + scol];
        }
    };

    f32x4 lacc = {0.f, 0.f, 0.f, 0.f};
    stageKbig(0, 0);
    LGKM_BARRIER();
    for (int c = 0; c < nch; ++c) {
        const int b = c & 1;
        if (c + 1 < nch) stageKbig(c + 1, b ^ 1);
        const short* kb = lds + b * (128 * 72);
        #pragma unroll
        for (int t = 0; t < 2; ++t) {
            const int kt = c * 2 + t;
            if (kt >= nkt) break;
            f32x4 s[4] = {};
            __builtin_amdgcn_s_setprio(1);
            #pragma unroll
            for (int ks = 0; ks < 2; ++ks) {
                bf16x8 qf = ks ? qf1 : qf0;
                #pragma unroll
                for (int n = 0; n < 4; ++n) {
                    bf16x8 kf = *(const bf16x8*)
                        &kb[(t * 64 + n * 16 + l15) * 72 + ks * 32 + lq * 8];
                    s[n] = mfma16(kf, qf, s[n]);
                }
            }
            __builtin_amdgcn_s_setprio(0);
            if (kt == qt) {  // diagonal: mask k > q
                #pragma unroll
                for (int n = 0; n < 4; ++n) {
                    int kb0 = kt * 64 + n * 16 + lq * 4;
                    #pragma unroll
                    for (int r = 0; r < 4; ++r)
                        lacc[n] += (kb0 + r <= myq) ? exp2f(s[n][r] * SC) : 0.f;
                }
            } else {
                #pragma unroll
                for (int n = 0; n < 4; ++n)
                    #pragma unroll
                    for (int r = 0; r < 4; ++r)
                        lacc[n] += exp2f(s[n][r] * SC);
            }
        }
        LGKM_BARRIER();
    }
    float lsum = (lacc[0] + lacc[1]) + (lacc[2] + lacc[3]);
    lsum += __shfl_xor(lsum, 16);
    lsum += __shfl_xor(lsum, 32);
    const float nlog = -__log2f(lsum);   // fold 1/lsum into the exponent

    // ---- phase 2: recompute S, weight stores, P@V; reg-staged K/V ----
    short* Ks2 = lds;                       // [2][64*72]
    short* Vs2 = lds + 2 * 64 * 72;         // [2][64*72]
    short* Psw = lds + 4 * 64 * 72 + wid * (16 * 72);

    bf16x8 krg0, krg1, vrg0, vrg1;          // staged tile (named: rule #20)
    auto loadKV = [&](int kt) {
        krg0 = *(const bf16x8*)&kbase[(size_t)(kt * 64 + srow) * DM + scol];
        krg1 = *(const bf16x8*)&kbase[(size_t)(kt * 64 + srow + 32) * DM + scol];
        vrg0 = *(const bf16x8*)&vbase[(size_t)srow * TSEQ + kt * 64 + scol];
        vrg1 = *(const bf16x8*)&vbase[(size_t)(srow + 32) * TSEQ + kt * 64 + scol];
    };
    auto writeKV = [&](int b) {
        short* kd = Ks2 + b * (64 * 72);
        short* vd = Vs2 + b * (64 * 72);
        *(bf16x8*)&kd[srow * 72 + scol] = krg0;
        *(bf16x8*)&kd[(srow + 32) * 72 + scol] = krg1;
        *(bf16x8*)&vd[srow * 72 + scol] = vrg0;
        *(bf16x8*)&vd[(srow + 32) * 72 + scol] = vrg1;
    };

    float* wq = Wout + (size_t)h * TSEQ * TSEQ + (size_t)myq * TSEQ;
    f32x4 o[4] = {};
    loadKV(0);
    writeKV(0);
    LGKM_BARRIER();
    for (int kt = 0; kt < nkt; ++kt) {
        const int b = kt & 1;
        const bool more = (kt + 1 < nkt);
        if (more) {
            loadKV(kt + 1);                       // issue loads early
            __builtin_amdgcn_sched_barrier(0);    // pin: loads above compute
        }
        f32x4 s[4] = {};
        __builtin_amdgcn_s_setprio(1);
        #pragma unroll
        for (int ks = 0; ks < 2; ++ks) {
            bf16x8 qf = ks ? qf1 : qf0;
            #pragma unroll
            for (int n = 0; n < 4; ++n) {
                bf16x8 kf = *(const bf16x8*)
                    &Ks2[b * (64 * 72) + (n * 16 + l15) * 72 + ks * 32 + lq * 8];
                s[n] = mfma16(kf, qf, s[n]);
            }
        }
        __builtin_amdgcn_s_setprio(0);
        const bool diag = (kt == qt);
        #pragma unroll
        for (int n = 0; n < 4; ++n) {
            const int kb0 = kt * 64 + n * 16 + lq * 4;
            f32x4 p;
            #pragma unroll
            for (int r = 0; r < 4; ++r) {
                float e = exp2f(fmaf(s[n][r], SC, nlog));  // normalized
                p[r] = (diag && (kb0 + r > myq)) ? 0.f : e;
            }
            *(f32x4*)(wq + kb0) = p;              // plain store: L2-merged
            uint2 pv;
            pv.x = pk2(p[0], p[1]);
            pv.y = pk2(p[2], p[3]);
            *(uint2*)&Psw[l15 * 72 + n * 16 + lq * 4] = pv;
        }
        // P @ V: A-frag = P (q rows) from per-wave Ps, B-frag = V^T from LDS
        __builtin_amdgcn_s_setprio(1);
        #pragma unroll
        for (int ks = 0; ks < 2; ++ks) {
            bf16x8 pf = *(bf16x8*)&Psw[l15 * 72 + ks * 32 + lq * 8];
            #pragma unroll
            for (int n = 0; n < 4; ++n) {
                bf16x8 vf = *(const bf16x8*)
                    &Vs2[b * (64 * 72) + (n * 16 + l15) * 72 + ks * 32 + lq * 8];
                o[n] = mfma16(pf, vf, o[n]);
            }
        }
        __builtin_amdgcn_s_setprio(0);
        if (more) {
            __builtin_amdgcn_sched_barrier(0);    // pin: ds_write after stores
            writeKV(b ^ 1);                       // reg -> LDS, no vmcnt(0)
        }
        LGKM_BARRIER();
    }

    // ---- epilogue: O (row = q0+wid*16+lq*4+r, col = h*64+n*16+l15) ----
    #pragma unroll
    for (int n = 0; n < 4; ++n) {
        int col = h * HDIM + n * 16 + l15;
        #pragma unroll
        for (int r = 0; r < 4; ++r) {
            int row = q0 + wid * 16 + lq * 4 + r;
            AttnO[(size_t)row * DM + col] = o[n][r];
        }
    }
}

extern "C" void kernel_launch(void* const* d_in, const int* in_sizes, int n_in,
                              void* d_out, int out_size, void* d_ws, size_t ws_size,
                              hipStream_t stream)
{
    const float* q_in = (const float*)d_in[0];
    const float* k_in = (const float*)d_in[1];
    const float* v_in = (const float*)d_in[2];
    // d_in[3] = causal mask (triu, k=1) — structure known, not read
    const float* Wq_w = (const float*)d_in[4];
    const float* Wq_b = (const float*)d_in[5];
    const float* Wk_w = (const float*)d_in[6];
    const float* Wk_b = (const float*)d_in[7];
    const float* Wv_w = (const float*)d_in[8];
    const float* Wv_b = (const float*)d_in[9];
    const float* W0_w = (const float*)d_in[10];
    const float* W0_b = (const float*)d_in[11];

    float* out  = (float*)d_out;                       // [4096][768] fp32
    float* wout = out + (size_t)TSEQ * DM;             // [12][4096][4096] fp32

    short* Qb = (short*)d_ws;                          // [4096][768] bf16
    short* Kb = Qb + (size_t)TSEQ * DM;                // [4096][768] bf16
    short* Vt = Kb + (size_t)TSEQ * DM;                // [768][4096] bf16 (V^T)
    float* AttnO = (float*)(Vt + (size_t)TSEQ * DM);   // [4096][768] fp32

    gemm_qkv<<<576, 512, 0, stream>>>(
        q_in, k_in, v_in, Wq_w, Wq_b, Wk_w, Wk_b, Wv_w, Wv_b, Qb, Kb, Vt);
    attn_fused<<<dim3(64, NHEAD), 256, 0, stream>>>(Qb, Kb, Vt, wout, AttnO);
    gemm_out<<<192, 512, 0, stream>>>(AttnO, W0_w, W0_b, out);
}